// Round 1
// baseline (120.781 us; speedup 1.0000x reference)
//
#include <hip/hip_runtime.h>
#include <utility>

// ---------------------------------------------------------------------------
// Compile-time port of the reference's _su2_cg / _q / wigner_3j.
// All Wigner-3j coefficients are computed by the C++ compiler at constexpr
// time and baked into the kernel as immediates (sparse nonzero table).
// ---------------------------------------------------------------------------
namespace w3j {

constexpr int NP = 15;
// PATHS = (i_in1, i_in2, i_out), same order as reference (weight indexing!)
constexpr int P1[NP] = {0,0,0,1,1,1,1,1,1,2,2,2,2,2,2};
constexpr int P2[NP] = {0,1,2,0,1,1,1,2,2,0,1,1,2,2,2};
constexpr int P3[NP] = {0,1,2,1,0,1,2,1,2,2,1,2,0,1,2};
constexpr int BASE[3] = {0,1,4};   // offset of l-block within the 9-wide irrep vector

constexpr double cfact(int n){ double r = 1.0; for (int i = 2; i <= n; ++i) r *= i; return r; }
constexpr double csqrt(double x){
  double g = x > 1.0 ? x : 1.0;
  for (int i = 0; i < 64; ++i){ double ng = 0.5*(g + x/g); if (ng == g) break; g = ng; }
  return g;
}
constexpr double neg1pow(int n){ return (n & 1) ? -1.0 : 1.0; }
constexpr int imax3(int a,int b,int c){ int m = a > b ? a : b; return m > c ? m : c; }
constexpr int imin3(int a,int b,int c){ int m = a < b ? a : b; return m < c ? m : c; }

constexpr double su2_cg(int j1,int j2,int j3,int m1,int m2,int m3){
  if (m3 != m1 + m2) return 0.0;
  int vmin = imax3(-j1 + j2 + m3, -j1 + m1, 0);
  int vmax = imin3(j2 + j3 + m1, j3 - j1 + j2, j3 + m3);
  double C = csqrt((2*j3 + 1) * cfact(j3 + j1 - j2) * cfact(j3 - j1 + j2) * cfact(j1 + j2 - j3)
                   * cfact(j3 + m3) * cfact(j3 - m3)
                   / (cfact(j1 + j2 + j3 + 1) * cfact(j1 - m1) * cfact(j1 + m1)
                      * cfact(j2 - m2) * cfact(j2 + m2)));
  double S = 0.0;
  for (int v = vmin; v <= vmax; ++v)
    S += neg1pow(v + j2 + m2) * cfact(j2 + j3 + m1 - v) * cfact(j1 - m1 + v)
         / (cfact(v) * cfact(j3 - j1 + j2 - v) * cfact(j3 + m3 - v) * cfact(v + j1 - j2 - m3));
  return C * S;
}

struct cplx { double re, im; };
constexpr cplx cmul(cplx a, cplx b){ return { a.re*b.re - a.im*b.im, a.re*b.im + a.im*b.re }; }
constexpr cplx cadd(cplx a, cplx b){ return { a.re + b.re, a.im + b.im }; }

struct QM { cplx q[5][5]; };
constexpr QM qmat(int l){
  QM Q{};
  const double is2 = 1.0 / csqrt(2.0);
  for (int m = -l; m < 0; ++m){
    Q.q[l+m][l-m] = cplx{ is2, 0.0 };     // q[l+m, l+|m|]
    Q.q[l+m][l+m] = cplx{ 0.0, -is2 };    // q[l+m, l-|m|]
  }
  Q.q[l][l] = cplx{ 1.0, 0.0 };
  for (int m = 1; m <= l; ++m){
    double s = neg1pow(m);
    Q.q[l+m][l+m] = cplx{ s*is2, 0.0 };
    Q.q[l+m][l-m] = cplx{ 0.0, s*is2 };
  }
  cplx f{1.0, 0.0};
  for (int t = 0; t < l; ++t) f = cmul(f, cplx{0.0, -1.0});   // (-i)^l
  for (int a = 0; a < 2*l+1; ++a) for (int b = 0; b < 2*l+1; ++b) Q.q[a][b] = cmul(Q.q[a][b], f);
  return Q;
}

// Effective coeff = sqrt(2*l3+1) * wigner_3j(l1,l2,l3); the internal
// /sqrt(2*l3+1) of wigner_3j cancels against _W3J's prefactor, so we
// einsum with the RAW CG tensor.
struct W3 { double w[5][5][5]; };
constexpr W3 wig(int l1,int l2,int l3){
  const int d1 = 2*l1+1, d2 = 2*l2+1, d3 = 2*l3+1;
  double C[5][5][5] = {};
  for (int a = 0; a < d1; ++a) for (int b = 0; b < d2; ++b) for (int c = 0; c < d3; ++c)
    C[a][b][c] = su2_cg(l1, l2, l3, a - l1, b - l2, c - l3);
  const QM q1 = qmat(l1), q2 = qmat(l2), q3 = qmat(l3);
  // W[j,l,m] = sum_{i,k,n} q1[i,j] q2[k,l] conj(q3[n,m]) C[i,k,n]  (staged)
  cplx T1[5][5][5] = {};
  for (int j = 0; j < d1; ++j) for (int k = 0; k < d2; ++k) for (int n = 0; n < d3; ++n){
    cplx s{0,0};
    for (int i = 0; i < d1; ++i) s = cadd(s, cmul(q1.q[i][j], cplx{ C[i][k][n], 0.0 }));
    T1[j][k][n] = s;
  }
  cplx T2[5][5][5] = {};
  for (int j = 0; j < d1; ++j) for (int l = 0; l < d2; ++l) for (int n = 0; n < d3; ++n){
    cplx s{0,0};
    for (int k = 0; k < d2; ++k) s = cadd(s, cmul(q2.q[k][l], T1[j][k][n]));
    T2[j][l][n] = s;
  }
  W3 W{};
  for (int j = 0; j < d1; ++j) for (int l = 0; l < d2; ++l) for (int m = 0; m < d3; ++m){
    cplx s{0,0};
    for (int n = 0; n < d3; ++n)
      s = cadd(s, cmul(cplx{ q3.q[n][m].re, -q3.q[n][m].im }, T2[j][l][n]));
    W.w[j][l][m] = s.re;
  }
  return W;
}

// Separate constexpr variables -> each gets its own constexpr-step budget.
constexpr W3 W_00 = wig(0,0,0);
constexpr W3 W_01 = wig(0,1,1);
constexpr W3 W_02 = wig(0,2,2);
constexpr W3 W_03 = wig(1,0,1);
constexpr W3 W_04 = wig(1,1,0);
constexpr W3 W_05 = wig(1,1,1);
constexpr W3 W_06 = wig(1,1,2);
constexpr W3 W_07 = wig(1,2,1);
constexpr W3 W_08 = wig(1,2,2);
constexpr W3 W_09 = wig(2,0,2);
constexpr W3 W_10 = wig(2,1,1);
constexpr W3 W_11 = wig(2,1,2);
constexpr W3 W_12 = wig(2,2,0);
constexpr W3 W_13 = wig(2,2,1);
constexpr W3 W_14 = wig(2,2,2);

struct Entry { int p, gi, gj, gk; float v; };
struct Table { Entry e[615]; int n; };
constexpr Table build(){
  const W3 WS[NP] = { W_00,W_01,W_02,W_03,W_04,W_05,W_06,W_07,
                      W_08,W_09,W_10,W_11,W_12,W_13,W_14 };
  Table t{};
  for (int p = 0; p < NP; ++p){
    const int l1 = P1[p], l2 = P2[p], l3 = P3[p];
    for (int i = 0; i < 2*l1+1; ++i)
      for (int j = 0; j < 2*l2+1; ++j)
        for (int k = 0; k < 2*l3+1; ++k){
          double v = WS[p].w[i][j][k];
          if (v > 1e-12 || v < -1e-12){
            t.e[t.n] = Entry{ p, BASE[l1] + i, BASE[l2] + j, BASE[l3] + k, (float)v };
            ++t.n;
          }
        }
  }
  return t;
}
constexpr Table TBL = build();
constexpr int NNZ = TBL.n;

} // namespace w3j

// ---------------------------------------------------------------------------
// Kernel: one thread per (row n, channel u). All coefficient indices are
// compile-time constants (template-unrolled over the sparse table), so the
// whole contraction is straight-line register code. Memory-bound by design.
// ---------------------------------------------------------------------------
template<int E>
__device__ __forceinline__ void apply_one(const float (&xx)[9], const float (&yv)[9],
                                          const float (&wp)[w3j::NP], float (&oo)[9]){
  constexpr w3j::Entry en = w3j::TBL.e[E];
  // wp[p]*xx[gi] is CSE'd across entries sharing (p, gi); en.v is an immediate.
  oo[en.gk] = fmaf(wp[en.p] * xx[en.gi] * en.v, yv[en.gj], oo[en.gk]);
}

template<int... Es>
__device__ __forceinline__ void apply_all(std::integer_sequence<int, Es...>,
                                          const float (&xx)[9], const float (&yv)[9],
                                          const float (&wp)[w3j::NP], float (&oo)[9]){
  (apply_one<Es>(xx, yv, wp, oo), ...);
}

__global__ __launch_bounds__(256)
void tp_rescale_kernel(const float* __restrict__ x, const float* __restrict__ y,
                       const float* __restrict__ w, const float* __restrict__ b,
                       float* __restrict__ out, int nrows)
{
  const int t = threadIdx.x;
  const int u = t & 63;                       // channel
  const long n = (long)blockIdx.x * 4 + (t >> 6);  // row (wave == one row)
  if (n >= nrows) return;

  const float* __restrict__ xr = x + n * 576;
  const float* __restrict__ yr = y + n * 9;

  float xx[9], yv[9], wp[w3j::NP], oo[9];

  xx[0] = xr[u];                              // l=0 block: col u
  #pragma unroll
  for (int i = 0; i < 3; ++i) xx[1 + i] = xr[64 + 3*u + i];    // l=1: col 64+3u+i
  #pragma unroll
  for (int k = 0; k < 5; ++k) xx[4 + k] = xr[256 + 5*u + k];   // l=2: col 256+5u+k

  #pragma unroll
  for (int j = 0; j < 9; ++j) yv[j] = yr[j];  // wave-uniform broadcast

  #pragma unroll
  for (int p = 0; p < w3j::NP; ++p) wp[p] = w[p * 64 + u];

  #pragma unroll
  for (int k = 0; k < 9; ++k) oo[k] = 0.0f;

  apply_all(std::make_integer_sequence<int, w3j::NNZ>{}, xx, yv, wp, oo);

  float* __restrict__ orow = out + n * 576;
  orow[u] = oo[0] + b[u];                     // bias only on the 0e slice
  #pragma unroll
  for (int i = 0; i < 3; ++i) orow[64 + 3*u + i] = oo[1 + i];
  #pragma unroll
  for (int k = 0; k < 5; ++k) orow[256 + 5*u + k] = oo[4 + k];
}

extern "C" void kernel_launch(void* const* d_in, const int* in_sizes, int n_in,
                              void* d_out, int out_size, void* d_ws, size_t ws_size,
                              hipStream_t stream) {
  const float* x = (const float*)d_in[0];
  const float* y = (const float*)d_in[1];
  const float* w = (const float*)d_in[2];
  const float* b = (const float*)d_in[3];
  float* out = (float*)d_out;

  const int nrows = in_sizes[0] / 576;        // 131072
  const int blocks = (nrows + 3) / 4;         // 4 rows per 256-thread block

  hipLaunchKernelGGL(tp_rescale_kernel, dim3(blocks), dim3(256), 0, stream,
                     x, y, w, b, out, nrows);
}